// Round 12
// baseline (206.829 us; speedup 1.0000x reference)
//
#include <hip/hip_runtime.h>
#include <math.h>

#define EPS 1e-5f
#define SLOPE 0.2f

typedef unsigned short u16;
typedef unsigned int u32;
typedef __attribute__((ext_vector_type(4))) float f32x4;
typedef __attribute__((ext_vector_type(16))) float f32x16;
typedef __attribute__((ext_vector_type(8))) short s16x8;
typedef __attribute__((ext_vector_type(4))) short s16x4;
typedef __attribute__((ext_vector_type(4))) u32 u32x4;

__device__ __forceinline__ float lrelu(float x){ return x >= 0.f ? x : SLOPE*x; }

__device__ __forceinline__ u16 f2b(float x){
  u32 u = __float_as_uint(x);
  u32 r = (u + 0x7FFFu + ((u >> 16) & 1u)) >> 16;
  return (u16)r;
}
__device__ __forceinline__ float b2f(short v){
  return __uint_as_float(((u32)(u16)v) << 16);
}
// LDS staging swizzle (T2): involution on bits 4-6 keyed by bits 9-11
__device__ __forceinline__ u32 swz(u32 a){ return a ^ (((a>>9)&7u)<<4); }

// ---------- NCHW f32 [4,256,32,32] -> NHWC bf16 [4,1024,256] (LDS transpose)
__global__ void k_tr(const float* __restrict__ x, u16* __restrict__ xh){
  __shared__ float t[32][33];
  int b = blockIdx.x>>8; int c0 = ((blockIdx.x>>5)&7)*32; int p0 = (blockIdx.x&31)*32;
  int tx = threadIdx.x&31, ty = threadIdx.x>>5;
  #pragma unroll
  for(int r=0;r<32;r+=8)
    t[ty+r][tx] = x[((size_t)(b*256 + c0+ty+r))*1024 + p0 + tx];
  __syncthreads();
  #pragma unroll
  for(int r=0;r<32;r+=8)
    xh[((size_t)(b*1024 + p0+ty+r))*256 + c0 + tx] = f2b(t[tx][ty+r]);
}

// ---------- bilinear x2 upsample (align_corners) NHWC bf16
__global__ void k_up8(const u16* __restrict__ xh, u16* __restrict__ u){
  int idx = blockIdx.x*256 + threadIdx.x;
  int cg = idx & 31;
  int ow = (idx>>5) & 63; int oh = (idx>>11)&63; int b = idx>>17;
  const float st = 31.0f/63.0f;
  float fh = oh*st, fw = ow*st;
  int h0=(int)fh, w0=(int)fw;
  float wh = fh-(float)h0, ww = fw-(float)w0;
  int h1=min(h0+1,31), w1=min(w0+1,31);
  const u16* xb = xh + ((size_t)b*1024)*256 + cg*8;
  s16x8 a = *(const s16x8*)(xb + (size_t)(h0*32+w0)*256);
  s16x8 bb= *(const s16x8*)(xb + (size_t)(h0*32+w1)*256);
  s16x8 c = *(const s16x8*)(xb + (size_t)(h1*32+w0)*256);
  s16x8 d = *(const s16x8*)(xb + (size_t)(h1*32+w1)*256);
  u16 o[8];
  #pragma unroll
  for(int j=0;j<8;++j){
    float top = b2f(a[j]) + (b2f(bb[j])-b2f(a[j]))*ww;
    float bot = b2f(c[j]) + (b2f(d[j])-b2f(c[j]))*ww;
    o[j] = f2b(top + (bot-top)*wh);
  }
  *(s16x8*)(u + (size_t)idx*8) = *(s16x8*)o;
}

// ---------- all weight transforms fused
__global__ void k_wall(const float* __restrict__ W_up, const float* __restrict__ W_r0,
                       const float* __restrict__ W_r1, const float* __restrict__ Wq,
                       const float* __restrict__ Wk, const float* __restrict__ Wv,
                       u16* __restrict__ wtu, u16* __restrict__ wtr0,
                       u16* __restrict__ wtr1, u16* __restrict__ wqk,
                       u16* __restrict__ wv){
  int idx = blockIdx.x*256 + threadIdx.x;
  if(idx < 294912){
    int ci = idx&255, t2 = idx>>8; int tap = t2%9, co = t2/9;
    wtu[idx] = f2b(W_up[((size_t)co*256+ci)*9 + tap]);
  } else if(idx < 442368){
    int i2 = idx - 294912;
    int ci = i2&127, t2 = i2>>7; int tap = t2%9, co = t2/9;
    wtr0[i2] = f2b(W_r0[((size_t)co*128+ci)*9 + tap]);
  } else if(idx < 589824){
    int i2 = idx - 442368;
    int ci = i2&127, t2 = i2>>7; int tap = t2%9, co = t2/9;
    wtr1[i2] = f2b(W_r1[((size_t)co*128+ci)*9 + tap]);
  } else if(idx < 606208){
    int i2 = idx - 589824;
    wqk[i2] = f2b(i2 < 8192 ? Wq[i2] : Wk[i2-8192]);
  } else {
    int i2 = idx - 606208;
    wv[i2] = f2b(Wv[i2]);
  }
}

// ---------- implicit-GEMM 3x3 conv (MFMA) + BN + LReLU, NHWC bf16
// BM=128 px x BN=64 co per block, 8 waves (wave = 32 px x 32 co).
// Same block tile as round 11 (same traffic), 2x waves/CU for latency hiding.
// kc outer: per-kc A window (4 rows x 64 px x 32 ci = 16KB) L1-resident, shared by 8 waves.
template<int CIN>
__global__ __launch_bounds__(512) void k_cmfma(
    const u16* __restrict__ xin, const u16* __restrict__ wt,
    const float* __restrict__ bias,
    const float* __restrict__ g, const float* __restrict__ be,
    const float* __restrict__ mm, const float* __restrict__ vv,
    u16* __restrict__ out)
{
  constexpr int K = CIN*9;
  int blk = blockIdx.x;
  int mt = blk & 31;
  int nt = (blk>>5) & 1;
  int b  = blk >> 6;
  int tid = threadIdx.x;
  int wid = tid>>6, lane = tid&63;
  int gq = lane>>4, lr = lane&15;
  int g8 = gq*8;
  int pxw = wid&3, cow = wid>>2;
  int mb = mt*128 + pxw*32;
  int h = mb>>6, w0 = mb&63;
  int cob = nt*64 + cow*32;

  f32x4 acc[2][2];
  #pragma unroll
  for(int pf=0;pf<2;++pf)
    #pragma unroll
    for(int cf=0;cf<2;++cf) acc[pf][cf]=(f32x4)0.f;

  const u16* xb = xin + (size_t)b*4096*CIN;
  const u16* wr = wt + (size_t)(cob+lr)*K + g8;

  for(int kc=0;kc<CIN/32;++kc){
    for(int dy=-1; dy<=1; ++dy){
      int hh = h+dy;
      if(hh<0 || hh>63) continue;
      #pragma unroll
      for(int dx=-1; dx<=1; ++dx){
        int tap = (dy+1)*3 + (dx+1);
        const u16* wtap = wr + tap*CIN + kc*32;
        const u16* ar[2]; bool av[2];
        #pragma unroll
        for(int pf=0;pf<2;++pf){
          int ww = w0 + pf*16 + lr + dx;
          av[pf] = (ww>=0)&&(ww<64);
          int wc = ww<0?0:(ww>63?63:ww);
          ar[pf] = xb + ((size_t)hh*64 + wc)*CIN + kc*32 + g8;
        }
        s16x8 af[2];
        #pragma unroll
        for(int pf=0;pf<2;++pf){
          s16x8 t = *(const s16x8*)(ar[pf]);
          af[pf] = av[pf] ? t : (s16x8)0;
        }
        s16x8 bfr[2];
        #pragma unroll
        for(int cf=0;cf<2;++cf)
          bfr[cf] = *(const s16x8*)(wtap + (size_t)cf*16*K);
        #pragma unroll
        for(int pf=0;pf<2;++pf)
          #pragma unroll
          for(int cf=0;cf<2;++cf)
            acc[pf][cf] = __builtin_amdgcn_mfma_f32_16x16x32_bf16(af[pf], bfr[cf], acc[pf][cf],0,0,0);
      }
    }
  }
  #pragma unroll
  for(int cf=0;cf<2;++cf){
    int co = cob + cf*16 + lr;
    float sc = g[co]*rsqrtf(vv[co]+EPS);
    float sh = be[co] - mm[co]*sc;
    if(bias) sh += bias[co]*sc;
    #pragma unroll
    for(int pf=0;pf<2;++pf){
      #pragma unroll
      for(int r=0;r<4;++r){
        int pix = mb + pf*16 + gq*4 + r;
        float v_ = acc[pf][cf][r]*sc + sh;
        out[((size_t)b*4096 + pix)*128 + co] = f2b(lrelu(v_));
      }
    }
  }
}

// ---------- fused q,k projection
__global__ __launch_bounds__(128) void k_projqk(
  const u16* __restrict__ x2b, const u16* __restrict__ wqk,
  const float* __restrict__ bq, const float* __restrict__ bk,
  u16* __restrict__ qbf, u16* __restrict__ kbf)
{
  int blk = blockIdx.x;
  int nt = blk & 1;
  int mt = blk >> 1;
  int wid = threadIdx.x>>6, lane = threadIdx.x&63;
  int gq=lane>>4, lr=lane&15, g8=gq*8;
  int mb = mt*64 + wid*32;
  int cob = nt*64;
  f32x4 acc[2][4];
  #pragma unroll
  for(int pf=0;pf<2;++pf)
    #pragma unroll
    for(int cf=0;cf<4;++cf) acc[pf][cf]=(f32x4)0.f;
  const u16* xr0 = x2b + (size_t)(mb+lr)*128 + g8;
  const u16* xr1 = x2b + (size_t)(mb+16+lr)*128 + g8;
  const u16* wr  = wqk + (size_t)(cob+lr)*128 + g8;
  #pragma unroll
  for(int kc=0;kc<4;++kc){
    s16x8 a0 = *(const s16x8*)(xr0 + kc*32);
    s16x8 a1 = *(const s16x8*)(xr1 + kc*32);
    s16x8 bfr[4];
    #pragma unroll
    for(int cf=0;cf<4;++cf) bfr[cf] = *(const s16x8*)(wr + (size_t)cf*16*128 + kc*32);
    #pragma unroll
    for(int cf=0;cf<4;++cf){
      acc[0][cf] = __builtin_amdgcn_mfma_f32_16x16x32_bf16(a0, bfr[cf], acc[0][cf],0,0,0);
      acc[1][cf] = __builtin_amdgcn_mfma_f32_16x16x32_bf16(a1, bfr[cf], acc[1][cf],0,0,0);
    }
  }
  #pragma unroll
  for(int cf=0;cf<4;++cf){
    int co = cob + cf*16 + lr;
    float bi = co<64 ? bq[co] : bk[co-64];
    #pragma unroll
    for(int pf=0;pf<2;++pf){
      #pragma unroll
      for(int r=0;r<4;++r){
        int pix = mb + pf*16 + gq*4 + r;
        float v_ = acc[pf][cf][r] + bi;
        if(co<64) qbf[(size_t)pix*64 + co] = f2b(v_);
        else      kbf[(size_t)pix*64 + (co-64)] = f2b(v_);
      }
    }
  }
}

// ---------- v projection, transposed output: vbf[b][co][pix]
__global__ __launch_bounds__(128) void k_projv(
  const u16* __restrict__ x2b, const u16* __restrict__ wv,
  const float* __restrict__ bv, u16* __restrict__ vbf)
{
  int blk = blockIdx.x;
  int cot = blk & 3;
  int pt  = (blk>>2) & 31;
  int b   = blk >> 7;
  int wid = threadIdx.x>>6, lane = threadIdx.x&63;
  int gq=lane>>4, lr=lane&15, g8=gq*8;
  int cb = cot*32;
  int nb = pt*128 + wid*64;
  f32x4 acc[2][4];
  #pragma unroll
  for(int pf=0;pf<2;++pf)
    #pragma unroll
    for(int cf=0;cf<4;++cf) acc[pf][cf]=(f32x4)0.f;
  const u16* ar0 = wv + (size_t)(cb+lr)*128 + g8;
  const u16* ar1 = wv + (size_t)(cb+16+lr)*128 + g8;
  const u16* xr  = x2b + ((size_t)b*4096 + nb + lr)*128 + g8;
  #pragma unroll
  for(int kc=0;kc<4;++kc){
    s16x8 a0 = *(const s16x8*)(ar0+kc*32);
    s16x8 a1 = *(const s16x8*)(ar1+kc*32);
    s16x8 bfr[4];
    #pragma unroll
    for(int cf=0;cf<4;++cf) bfr[cf] = *(const s16x8*)(xr + (size_t)cf*16*128 + kc*32);
    #pragma unroll
    for(int cf=0;cf<4;++cf){
      acc[0][cf] = __builtin_amdgcn_mfma_f32_16x16x32_bf16(a0, bfr[cf], acc[0][cf],0,0,0);
      acc[1][cf] = __builtin_amdgcn_mfma_f32_16x16x32_bf16(a1, bfr[cf], acc[1][cf],0,0,0);
    }
  }
  #pragma unroll
  for(int pf=0;pf<2;++pf){
    #pragma unroll
    for(int r=0;r<4;++r){
      int co = cb + pf*16 + gq*4 + r;
      float bi = bv[co];
      #pragma unroll
      for(int cf=0;cf<4;++cf){
        int pix = nb + cf*16 + lr;
        vbf[((size_t)b*128+co)*4096 + pix] = f2b(acc[pf][cf][r] + bi);
      }
    }
  }
}

// ---------- MFMA flash attention v4: LDS-staged KV (XOR-swizzled), 64 q-rows/block
__global__ __launch_bounds__(512, 2) void k_fattn4(
    const u16* __restrict__ qbf, const u16* __restrict__ kbf,
    const u16* __restrict__ vbf, const u16* __restrict__ x2b,
    const u16* __restrict__ idbb, float* __restrict__ out){
  __shared__ char lds[2*49152 + 2048];   // 2 x (4x4KB K + 4x8KB V) + stats
  float* sst = (float*)(lds + 2*49152);  // [wid][ml][2]
  int tid = threadIdx.x;
  int wid = tid>>6, lane = tid&63;
  int ml = lane&31, hi = lane>>5;
  int g  = wid&1;        // row-group
  int s  = wid>>1;       // KV split 0..3
  int blk = blockIdx.x;
  int b  = blk&3;                                  // XCD-pinned batch
  int mt = ((blk>>3)<<1) | ((blk>>2)&1);           // 0..63
  int mbase = mt*64 + g*32;

  // Q B-fragments: col m = ml, k = kc*16 + hi*8 + j
  const u16* qp = qbf + ((size_t)b*4096 + mbase + ml)*64 + hi*8;
  s16x8 qf[4];
  #pragma unroll
  for(int kc=0;kc<4;++kc) qf[kc] = *(const s16x8*)(qp + kc*16);

  // staging descriptors: 6 x 16B chunks per thread per iteration (dest pre-swizzled)
  const u16* sgp[6]; u32 sdo[6];
  #pragma unroll
  for(int i=0;i<2;++i){
    int id = i*512 + tid;              // 0..1023 -> K
    int st = id>>8, r = (id>>3)&31, c = id&7;
    sgp[i] = kbf + (size_t)b*262144 + (size_t)(st*32 + r)*64 + c*8;
    sdo[i] = swz(st*4096 + ((u32)((c>>1)*64 + (c&1)*32 + r) << 4));
  }
  #pragma unroll
  for(int i=2;i<6;++i){
    int q2 = (i-2)*512 + tid;          // 0..2047 -> V
    int st = q2>>9, w = q2&511, row = w>>2, d = w&3;
    sgp[i] = vbf + ((size_t)b*128 + row)*4096 + st*32 + d*8;
    sdo[i] = swz(16384 + st*8192 + ((u32)((((row>>5)<<1) + (d>>1))*64 + (d&1)*32 + (row&31)) << 4));
  }

  f32x16 acc[4];
  #pragma unroll
  for(int cb=0;cb<4;++cb) acc[cb] = (f32x16)0.f;
  float mrun = -3.0e38f, lrun = 0.f;

  s16x8 stg[6];
  // prologue: stage tile-group 0 into buf0
  #pragma unroll
  for(int i=0;i<2;++i) stg[i] = *(const s16x8*)(sgp[i]);
  #pragma unroll
  for(int i=2;i<6;++i) stg[i] = *(const s16x8*)(sgp[i]);
  #pragma unroll
  for(int i=0;i<6;++i) *(s16x8*)(lds + sdo[i]) = stg[i];
  __syncthreads();

  for(int j=0;j<32;++j){
    int p = j&1;
    // issue next group's loads early (latency hides under compute)
    if(j<31){
      #pragma unroll
      for(int i=0;i<2;++i) stg[i] = *(const s16x8*)(sgp[i] + (size_t)(j+1)*8192);
      #pragma unroll
      for(int i=2;i<6;++i) stg[i] = *(const s16x8*)(sgp[i] + (size_t)(j+1)*128);
    }
    // ---- compute from buf p, split s
    char* Kb = lds + p*49152 + s*4096;
    char* Vb = lds + p*49152 + 16384 + s*8192;
    f32x16 sv = (f32x16)0.f;
    __builtin_amdgcn_s_setprio(1);
    #pragma unroll
    for(int kc=0;kc<4;++kc){
      s16x8 ka = *(const s16x8*)(Kb + swz((u32)((kc*64+lane)<<4)));
      sv = __builtin_amdgcn_mfma_f32_32x32x16_bf16(ka, qf[kc], sv, 0, 0, 0);
    }
    __builtin_amdgcn_s_setprio(0);
    float tm = sv[0];
    #pragma unroll
    for(int r=1;r<16;++r) tm = fmaxf(tm, sv[r]);
    tm = fmaxf(tm, __shfl_xor(tm, 32));
    if(__any(tm > mrun + 8.f)){
      float mnew = fmaxf(mrun, tm);
      float alpha = __expf(mrun - mnew);
      lrun *= alpha;
      #pragma unroll
      for(int cb=0;cb<4;++cb)
        #pragma unroll
        for(int r=0;r<16;++r) acc[cb][r] *= alpha;
      mrun = mnew;
    }
    float ps = 0.f;
    #pragma unroll
    for(int r=0;r<16;++r){ float pv = __expf(sv[r] - mrun); sv[r] = pv; ps += pv; }
    ps += __shfl_xor(ps, 32);
    lrun += ps;
    u32 pk[8];
    #pragma unroll
    for(int i=0;i<8;++i){
      u32 w_;
      asm("v_cvt_pk_bf16_f32 %0, %1, %2" : "=v"(w_) : "v"(sv[2*i]), "v"(sv[2*i+1]));
      pk[i] = w_;
    }
    asm volatile("v_permlane32_swap_b32 %0, %1" : "+v"(pk[0]), "+v"(pk[2]));
    asm volatile("v_permlane32_swap_b32 %0, %1" : "+v"(pk[1]), "+v"(pk[3]));
    asm volatile("v_permlane32_swap_b32 %0, %1" : "+v"(pk[4]), "+v"(pk[6]));
    asm volatile("v_permlane32_swap_b32 %0, %1" : "+v"(pk[5]), "+v"(pk[7]));
    u32x4 w0 = {pk[0], pk[1], pk[2], pk[3]};
    u32x4 w1 = {pk[4], pk[5], pk[6], pk[7]};
    s16x8 pb0 = __builtin_bit_cast(s16x8, w0);
    s16x8 pb1 = __builtin_bit_cast(s16x8, w1);
    __builtin_amdgcn_s_setprio(1);
    #pragma unroll
    for(int cb=0;cb<4;++cb){
      s16x8 va0 = *(const s16x8*)(Vb + swz((u32)(((cb*2+0)*64+lane)<<4)));
      s16x8 va1 = *(const s16x8*)(Vb + swz((u32)(((cb*2+1)*64+lane)<<4)));
      acc[cb] = __builtin_amdgcn_mfma_f32_32x32x16_bf16(va0, pb0, acc[cb], 0, 0, 0);
      acc[cb] = __builtin_amdgcn_mfma_f32_32x32x16_bf16(va1, pb1, acc[cb], 0, 0, 0);
    }
    __builtin_amdgcn_s_setprio(0);
    // ---- write next group into buf p^1
    if(j<31){
      #pragma unroll
      for(int i=0;i<6;++i) *(s16x8*)(lds + (p^1)*49152 + sdo[i]) = stg[i];
    }
    __syncthreads();
  }

  // stats
  if(hi == 0){
    sst[wid*64 + ml*2 + 0] = mrun;
    sst[wid*64 + ml*2 + 1] = lrun;
  }
  __syncthreads();
  // per-lane merge weights for (g, ml) over splits
  float mws[4], sws[4], Mx = -3.0e38f;
  #pragma unroll
  for(int s2=0;s2<4;++s2){ mws[s2] = sst[(s2*2+g)*64 + ml*2 + 0]; Mx = fmaxf(Mx, mws[s2]); }
  float lstar = 0.f;
  #pragma unroll
  for(int s2=0;s2<4;++s2){ sws[s2] = __expf(mws[s2]-Mx); lstar += sst[(s2*2+g)*64 + ml*2 + 1]*sws[s2]; }
  float inv = 1.f/lstar;
  int m = mbase + ml;

  // 4-phase combine over cb; dump region aliases staging buffers (32KB)
  float* dump = (float*)lds;
  #pragma unroll
  for(int cb=0;cb<4;++cb){
    #pragma unroll
    for(int r=0;r<16;++r)
      dump[wid*1024 + r*64 + lane] = acc[cb][r];
    __syncthreads();
    int c0 = cb*32 + s*8 + 4*hi;
    size_t rbase = ((size_t)b*4096 + m)*128 + c0;
    s16x4 xr = *(const s16x4*)(x2b + rbase);
    s16x4 ir = *(const s16x4*)(idbb + rbase);
    #pragma unroll
    for(int q=0;q<4;++q){
      int r = s*4 + q;
      float O = 0.f;
      #pragma unroll
      for(int s2=0;s2<4;++s2) O += sws[s2]*dump[(s2*2+g)*1024 + r*64 + lane];
      float val = O*inv + b2f(xr[q]) + b2f(ir[q]);
      out[((size_t)b*128 + c0 + q)*4096 + m] = lrelu(val);
    }
    __syncthreads();
  }
}

extern "C" void kernel_launch(void* const* d_in, const int* in_sizes, int n_in,
                              void* d_out, int out_size, void* d_ws, size_t ws_size,
                              hipStream_t stream) {
  const float* x    = (const float*)d_in[0];
  const float* W_up = (const float*)d_in[1];
  const float* b_up = (const float*)d_in[2];
  const float* g0   = (const float*)d_in[3];
  const float* be0  = (const float*)d_in[4];
  const float* m0   = (const float*)d_in[5];
  const float* v0   = (const float*)d_in[6];
  const float* W_r0 = (const float*)d_in[7];
  const float* g1   = (const float*)d_in[8];
  const float* be1  = (const float*)d_in[9];
  const float* m1   = (const float*)d_in[10];
  const float* v1   = (const float*)d_in[11];
  const float* W_r1 = (const float*)d_in[12];
  const float* g2   = (const float*)d_in[13];
  const float* be2  = (const float*)d_in[14];
  const float* m2   = (const float*)d_in[15];
  const float* v2   = (const float*)d_in[16];
  const float* Wq   = (const float*)d_in[17];
  const float* bq   = (const float*)d_in[18];
  const float* Wk   = (const float*)d_in[19];
  const float* bk   = (const float*)d_in[20];
  const float* Wv   = (const float*)d_in[21];
  const float* bv   = (const float*)d_in[22];

  float* ws = (float*)d_ws;
  u16* xh   = (u16*)(ws + 0);         // [4,1024,256]
  u16* ub   = (u16*)(ws + 524288);    // [4,4096,256]
  u16* idbb = (u16*)(ws + 2621440);   // [4,4096,128]
  u16* x1b  = (u16*)(ws + 3670016);   // [4,4096,128]
  u16* x2b  = (u16*)(ws + 4718592);   // [4,4096,128]
  u16* qbf  = (u16*)(ws + 5767168);   // [4,4096,64]
  u16* kbf  = (u16*)(ws + 6291456);   // [4,4096,64]
  u16* vbf  = (u16*)(ws + 6815744);   // [4,128,4096]
  u16* wtu  = (u16*)(ws + 7864320);   // [128,2304]
  u16* wtr0 = (u16*)(ws + 8011776);   // [128,1152]
  u16* wtr1 = (u16*)(ws + 8085504);   // [128,1152]
  u16* wqk  = (u16*)(ws + 8159232);   // [128,128]
  u16* wvb  = (u16*)(ws + 8167424);   // [128,128]
  float* out = (float*)d_out;

  // weight transforms (fused)
  k_wall<<<2432, 256, 0, stream>>>(W_up, W_r0, W_r1, Wq, Wk, Wv, wtu, wtr0, wtr1, wqk, wvb);
  // input layout + upsample
  k_tr<<<1024, 256, 0, stream>>>(x, xh);
  k_up8<<<2048, 256, 0, stream>>>(xh, ub);
  // convs (MFMA implicit GEMM, BM=128/BN=64 block tile, 8 waves/block)
  k_cmfma<256><<<256, 512, 0, stream>>>(ub, wtu, b_up, g0, be0, m0, v0, idbb);
  k_cmfma<128><<<256, 512, 0, stream>>>(idbb, wtr0, nullptr, g1, be1, m1, v1, x1b);
  k_cmfma<128><<<256, 512, 0, stream>>>(x1b, wtr1, nullptr, g2, be2, m2, v2, x2b);
  // projections
  k_projqk<<<512, 128, 0, stream>>>(x2b, wqk, bq, bk, qbf, kbf);
  k_projv<<<512, 128, 0, stream>>>(x2b, wvb, bv, vbf);
  // attention + residuals + lrelu (LDS-staged, swizzled)
  k_fattn4<<<256, 512, 0, stream>>>(qbf, kbf, vbf, x2b, idbb, out);
}

// Round 13
// 143.536 us; speedup vs baseline: 1.4410x; 1.4410x over previous
//
#include <hip/hip_runtime.h>
#include <math.h>

#define EPS 1e-5f
#define SLOPE 0.2f

typedef unsigned short u16;
typedef unsigned int u32;
typedef __attribute__((ext_vector_type(4))) float f32x4;
typedef __attribute__((ext_vector_type(16))) float f32x16;
typedef __attribute__((ext_vector_type(8))) short s16x8;
typedef __attribute__((ext_vector_type(4))) short s16x4;
typedef __attribute__((ext_vector_type(4))) u32 u32x4;

__device__ __forceinline__ float lrelu(float x){ return x >= 0.f ? x : SLOPE*x; }

__device__ __forceinline__ u16 f2b(float x){
  u32 u = __float_as_uint(x);
  u32 r = (u + 0x7FFFu + ((u >> 16) & 1u)) >> 16;
  return (u16)r;
}
__device__ __forceinline__ float b2f(short v){
  return __uint_as_float(((u32)(u16)v) << 16);
}
// LDS staging swizzle (T2): involution on bits 4-6 keyed by bits 9-11
__device__ __forceinline__ u32 swz(u32 a){ return a ^ (((a>>9)&7u)<<4); }

// ---------- NCHW f32 [4,256,32,32] -> kc-blocked bf16 [4][8kc][1024][32]
__global__ void k_tr(const float* __restrict__ x, u16* __restrict__ xh){
  __shared__ float t[32][33];
  int b = blockIdx.x>>8; int kc = (blockIdx.x>>5)&7; int p0 = (blockIdx.x&31)*32;
  int tx = threadIdx.x&31, ty = threadIdx.x>>5;
  #pragma unroll
  for(int r=0;r<32;r+=8)
    t[ty+r][tx] = x[((size_t)(b*256 + kc*32+ty+r))*1024 + p0 + tx];
  __syncthreads();
  #pragma unroll
  for(int r=0;r<32;r+=8)
    xh[((size_t)((b*8+kc)*1024) + p0+ty+r)*32 + tx] = f2b(t[tx][ty+r]);
}

// ---------- bilinear x2 upsample (align_corners), kc-blocked bf16 -> [4][8][4096][32]
__global__ void k_up8(const u16* __restrict__ xh, u16* __restrict__ u){
  int idx = blockIdx.x*256 + threadIdx.x;    // 524288: b(2) kc(3) pix(12) sub(2)
  int sub = (idx&3)*8;
  int pix = (idx>>2)&4095;
  int kc  = (idx>>14)&7;
  int b   = idx>>17;
  int ow = pix&63, oh = pix>>6;
  const float st = 31.0f/63.0f;
  float fh = oh*st, fw = ow*st;
  int h0=(int)fh, w0=(int)fw;
  float wh = fh-(float)h0, ww = fw-(float)w0;
  int h1=min(h0+1,31), w1=min(w0+1,31);
  const u16* xb = xh + (size_t)((b*8+kc)*1024)*32 + sub;
  s16x8 a = *(const s16x8*)(xb + (size_t)(h0*32+w0)*32);
  s16x8 bb= *(const s16x8*)(xb + (size_t)(h0*32+w1)*32);
  s16x8 c = *(const s16x8*)(xb + (size_t)(h1*32+w0)*32);
  s16x8 d = *(const s16x8*)(xb + (size_t)(h1*32+w1)*32);
  u16 o[8];
  #pragma unroll
  for(int j=0;j<8;++j){
    float top = b2f(a[j]) + (b2f(bb[j])-b2f(a[j]))*ww;
    float bot = b2f(c[j]) + (b2f(d[j])-b2f(c[j]))*ww;
    o[j] = f2b(top + (bot-top)*wh);
  }
  *(s16x8*)(u + (size_t)((b*8+kc)*4096 + pix)*32 + sub) = *(s16x8*)o;
}

// ---------- all weight transforms fused (blocked layouts)
// conv: [kc][tap][co(128)][32ci]; proj: [kc][o(128)][32ci]
__global__ void k_wall(const float* __restrict__ W_up, const float* __restrict__ W_r0,
                       const float* __restrict__ W_r1, const float* __restrict__ Wq,
                       const float* __restrict__ Wk, const float* __restrict__ Wv,
                       u16* __restrict__ wtu, u16* __restrict__ wtr0,
                       u16* __restrict__ wtr1, u16* __restrict__ wqk,
                       u16* __restrict__ wv){
  int idx = blockIdx.x*256 + threadIdx.x;
  if(idx < 294912){
    int ci = idx&31, co = (idx>>5)&127, t2 = idx>>12;
    int tap = t2%9, kc = t2/9;
    wtu[idx] = f2b(W_up[((size_t)co*256 + kc*32+ci)*9 + tap]);
  } else if(idx < 442368){
    int i2 = idx - 294912;
    int ci = i2&31, co = (i2>>5)&127, t2 = i2>>12;
    int tap = t2%9, kc = t2/9;
    wtr0[i2] = f2b(W_r0[((size_t)co*128 + kc*32+ci)*9 + tap]);
  } else if(idx < 589824){
    int i2 = idx - 442368;
    int ci = i2&31, co = (i2>>5)&127, t2 = i2>>12;
    int tap = t2%9, kc = t2/9;
    wtr1[i2] = f2b(W_r1[((size_t)co*128 + kc*32+ci)*9 + tap]);
  } else if(idx < 606208){
    int i2 = idx - 589824;
    int ci = i2&31, o = (i2>>5)&127, kc = i2>>12;
    wqk[i2] = f2b(o < 64 ? Wq[(size_t)o*128 + kc*32+ci] : Wk[(size_t)(o-64)*128 + kc*32+ci]);
  } else {
    int i2 = idx - 606208;
    int ci = i2&31, c = (i2>>5)&127, kc = i2>>12;
    wv[i2] = f2b(Wv[(size_t)c*128 + kc*32+ci]);
  }
}

// ---------- implicit-GEMM 3x3 conv (MFMA) + BN + LReLU, kc-blocked
// round-10 structure: BM=64 (2 waves x 32px x 64co), grid 512; coalesced 1KB loads
template<int CIN>
__global__ __launch_bounds__(128) void k_cmfma(
    const u16* __restrict__ xin, const u16* __restrict__ wt,
    const float* __restrict__ bias,
    const float* __restrict__ g, const float* __restrict__ be,
    const float* __restrict__ mm, const float* __restrict__ vv,
    u16* __restrict__ out)
{
  constexpr int KC = CIN/32;
  int blk = blockIdx.x;
  int mt = blk & 63;
  int nt = (blk>>6) & 1;
  int b  = blk >> 7;
  int wid = threadIdx.x>>6, lane = threadIdx.x&63;
  int gq = lane>>4, lr = lane&15;
  int g8 = gq*8;
  int mb = mt*64 + wid*32;
  int h = mb>>6, w0 = mb&63;
  int cob = nt*64;

  f32x4 acc[2][4];
  #pragma unroll
  for(int pf=0;pf<2;++pf)
    #pragma unroll
    for(int cf=0;cf<4;++cf) acc[pf][cf]=(f32x4)0.f;

  const u16* xb = xin + (size_t)b*KC*4096*32;

  for(int dy=-1; dy<=1; ++dy){
    int hh = h+dy;
    if(hh<0 || hh>63) continue;
    #pragma unroll
    for(int dx=-1; dx<=1; ++dx){
      int tap = (dy+1)*3 + (dx+1);
      const u16* ar[2]; bool av[2];
      #pragma unroll
      for(int pf=0;pf<2;++pf){
        int ww = w0 + pf*16 + lr + dx;
        av[pf] = (ww>=0)&&(ww<64);
        int wc = ww<0?0:(ww>63?63:ww);
        ar[pf] = xb + ((size_t)(hh*64 + wc))*32 + g8;
      }
      #pragma unroll
      for(int kc=0;kc<KC;++kc){
        s16x8 af[2];
        #pragma unroll
        for(int pf=0;pf<2;++pf){
          s16x8 t = *(const s16x8*)(ar[pf] + (size_t)kc*131072);
          af[pf] = av[pf] ? t : (s16x8)0;
        }
        const u16* wtap = wt + ((size_t)((kc*9+tap)*128) + cob + lr)*32 + g8;
        s16x8 bfr[4];
        #pragma unroll
        for(int cf=0;cf<4;++cf)
          bfr[cf] = *(const s16x8*)(wtap + cf*16*32);
        #pragma unroll
        for(int pf=0;pf<2;++pf)
          #pragma unroll
          for(int cf=0;cf<4;++cf)
            acc[pf][cf] = __builtin_amdgcn_mfma_f32_16x16x32_bf16(af[pf], bfr[cf], acc[pf][cf],0,0,0);
      }
    }
  }
  #pragma unroll
  for(int cf=0;cf<4;++cf){
    int co = cob + cf*16 + lr;
    float sc = g[co]*rsqrtf(vv[co]+EPS);
    float sh = be[co] - mm[co]*sc;
    if(bias) sh += bias[co]*sc;
    int kco = co>>5, ci = co&31;
    #pragma unroll
    for(int pf=0;pf<2;++pf){
      #pragma unroll
      for(int r=0;r<4;++r){
        int pix = mb + pf*16 + gq*4 + r;
        float v_ = acc[pf][cf][r]*sc + sh;
        out[((size_t)((b*4 + kco)*4096) + pix)*32 + ci] = f2b(lrelu(v_));
      }
    }
  }
}

// ---------- fused q,k projection (blocked x2b + blocked wqk)
__global__ __launch_bounds__(128) void k_projqk(
  const u16* __restrict__ x2b, const u16* __restrict__ wqk,
  const float* __restrict__ bq, const float* __restrict__ bk,
  u16* __restrict__ qbf, u16* __restrict__ kbf)
{
  int blk = blockIdx.x;
  int nt = blk & 1;
  int mt = blk >> 1;
  int wid = threadIdx.x>>6, lane = threadIdx.x&63;
  int gq=lane>>4, lr=lane&15, g8=gq*8;
  int gp = mt*64 + wid*32;
  int b = gp>>12, p = gp&4095;
  int cob = nt*64;
  f32x4 acc[2][4];
  #pragma unroll
  for(int pf=0;pf<2;++pf)
    #pragma unroll
    for(int cf=0;cf<4;++cf) acc[pf][cf]=(f32x4)0.f;
  const u16* xb = x2b + (size_t)b*4*4096*32;
  #pragma unroll
  for(int kc=0;kc<4;++kc){
    s16x8 a0 = *(const s16x8*)(xb + ((size_t)(kc*4096) + p + lr)*32 + g8);
    s16x8 a1 = *(const s16x8*)(xb + ((size_t)(kc*4096) + p + 16 + lr)*32 + g8);
    s16x8 bfr[4];
    #pragma unroll
    for(int cf=0;cf<4;++cf)
      bfr[cf] = *(const s16x8*)(wqk + ((size_t)(kc*128) + cob + cf*16 + lr)*32 + g8);
    #pragma unroll
    for(int cf=0;cf<4;++cf){
      acc[0][cf] = __builtin_amdgcn_mfma_f32_16x16x32_bf16(a0, bfr[cf], acc[0][cf],0,0,0);
      acc[1][cf] = __builtin_amdgcn_mfma_f32_16x16x32_bf16(a1, bfr[cf], acc[1][cf],0,0,0);
    }
  }
  #pragma unroll
  for(int cf=0;cf<4;++cf){
    int co = cob + cf*16 + lr;
    float bi = co<64 ? bq[co] : bk[co-64];
    #pragma unroll
    for(int pf=0;pf<2;++pf){
      #pragma unroll
      for(int r=0;r<4;++r){
        int pix = gp + pf*16 + gq*4 + r;
        float v_ = acc[pf][cf][r] + bi;
        if(co<64) qbf[(size_t)pix*64 + co] = f2b(v_);
        else      kbf[(size_t)pix*64 + (co-64)] = f2b(v_);
      }
    }
  }
}

// ---------- v projection (blocked inputs), output vbf[b][co][pix]
__global__ __launch_bounds__(128) void k_projv(
  const u16* __restrict__ x2b, const u16* __restrict__ wv,
  const float* __restrict__ bv, u16* __restrict__ vbf)
{
  int blk = blockIdx.x;
  int cot = blk & 3;
  int pt  = (blk>>2) & 31;
  int b   = blk >> 7;
  int wid = threadIdx.x>>6, lane = threadIdx.x&63;
  int gq=lane>>4, lr=lane&15, g8=gq*8;
  int cb = cot*32;
  int nb = pt*128 + wid*64;
  f32x4 acc[2][4];
  #pragma unroll
  for(int pf=0;pf<2;++pf)
    #pragma unroll
    for(int cf=0;cf<4;++cf) acc[pf][cf]=(f32x4)0.f;
  const u16* xb = x2b + (size_t)b*4*4096*32;
  #pragma unroll
  for(int kc=0;kc<4;++kc){
    s16x8 a0 = *(const s16x8*)(wv + ((size_t)(kc*128) + cb + lr)*32 + g8);
    s16x8 a1 = *(const s16x8*)(wv + ((size_t)(kc*128) + cb + 16 + lr)*32 + g8);
    s16x8 bfr[4];
    #pragma unroll
    for(int cf=0;cf<4;++cf)
      bfr[cf] = *(const s16x8*)(xb + ((size_t)(kc*4096) + nb + cf*16 + lr)*32 + g8);
    #pragma unroll
    for(int cf=0;cf<4;++cf){
      acc[0][cf] = __builtin_amdgcn_mfma_f32_16x16x32_bf16(a0, bfr[cf], acc[0][cf],0,0,0);
      acc[1][cf] = __builtin_amdgcn_mfma_f32_16x16x32_bf16(a1, bfr[cf], acc[1][cf],0,0,0);
    }
  }
  #pragma unroll
  for(int pf=0;pf<2;++pf){
    #pragma unroll
    for(int r=0;r<4;++r){
      int co = cb + pf*16 + gq*4 + r;
      float bi = bv[co];
      #pragma unroll
      for(int cf=0;cf<4;++cf){
        int pix = nb + cf*16 + lr;
        vbf[((size_t)b*128+co)*4096 + pix] = f2b(acc[pf][cf][r] + bi);
      }
    }
  }
}

// ---------- MFMA flash attention v4: LDS-staged KV (XOR-swizzled), 64 q-rows/block
__global__ __launch_bounds__(512, 2) void k_fattn4(
    const u16* __restrict__ qbf, const u16* __restrict__ kbf,
    const u16* __restrict__ vbf, const u16* __restrict__ x2b,
    const u16* __restrict__ idbb, float* __restrict__ out){
  __shared__ char lds[2*49152 + 2048];   // 2 x (4x4KB K + 4x8KB V) + stats
  float* sst = (float*)(lds + 2*49152);  // [wid][ml][2]
  int tid = threadIdx.x;
  int wid = tid>>6, lane = tid&63;
  int ml = lane&31, hi = lane>>5;
  int g  = wid&1;        // row-group
  int s  = wid>>1;       // KV split 0..3
  int blk = blockIdx.x;
  int b  = blk&3;                                  // XCD-pinned batch
  int mt = ((blk>>3)<<1) | ((blk>>2)&1);           // 0..63
  int mbase = mt*64 + g*32;

  // Q B-fragments: col m = ml, k = kc*16 + hi*8 + j
  const u16* qp = qbf + ((size_t)b*4096 + mbase + ml)*64 + hi*8;
  s16x8 qf[4];
  #pragma unroll
  for(int kc=0;kc<4;++kc) qf[kc] = *(const s16x8*)(qp + kc*16);

  // staging descriptors: 6 x 16B chunks per thread per iteration (dest pre-swizzled)
  const u16* sgp[6]; u32 sdo[6];
  #pragma unroll
  for(int i=0;i<2;++i){
    int id = i*512 + tid;              // 0..1023 -> K
    int st = id>>8, r = (id>>3)&31, c = id&7;
    sgp[i] = kbf + (size_t)b*262144 + (size_t)(st*32 + r)*64 + c*8;
    sdo[i] = swz(st*4096 + ((u32)((c>>1)*64 + (c&1)*32 + r) << 4));
  }
  #pragma unroll
  for(int i=2;i<6;++i){
    int q2 = (i-2)*512 + tid;          // 0..2047 -> V
    int st = q2>>9, w = q2&511, row = w>>2, d = w&3;
    sgp[i] = vbf + ((size_t)b*128 + row)*4096 + st*32 + d*8;
    sdo[i] = swz(16384 + st*8192 + ((u32)((((row>>5)<<1) + (d>>1))*64 + (d&1)*32 + (row&31)) << 4));
  }

  f32x16 acc[4];
  #pragma unroll
  for(int cb=0;cb<4;++cb) acc[cb] = (f32x16)0.f;
  float mrun = -3.0e38f, lrun = 0.f;

  s16x8 stg[6];
  // prologue: stage tile-group 0 into buf0
  #pragma unroll
  for(int i=0;i<2;++i) stg[i] = *(const s16x8*)(sgp[i]);
  #pragma unroll
  for(int i=2;i<6;++i) stg[i] = *(const s16x8*)(sgp[i]);
  #pragma unroll
  for(int i=0;i<6;++i) *(s16x8*)(lds + sdo[i]) = stg[i];
  __syncthreads();

  for(int j=0;j<32;++j){
    int p = j&1;
    // issue next group's loads early (latency hides under compute)
    if(j<31){
      #pragma unroll
      for(int i=0;i<2;++i) stg[i] = *(const s16x8*)(sgp[i] + (size_t)(j+1)*8192);
      #pragma unroll
      for(int i=2;i<6;++i) stg[i] = *(const s16x8*)(sgp[i] + (size_t)(j+1)*128);
    }
    // ---- compute from buf p, split s
    char* Kb = lds + p*49152 + s*4096;
    char* Vb = lds + p*49152 + 16384 + s*8192;
    f32x16 sv = (f32x16)0.f;
    __builtin_amdgcn_s_setprio(1);
    #pragma unroll
    for(int kc=0;kc<4;++kc){
      s16x8 ka = *(const s16x8*)(Kb + swz((u32)((kc*64+lane)<<4)));
      sv = __builtin_amdgcn_mfma_f32_32x32x16_bf16(ka, qf[kc], sv, 0, 0, 0);
    }
    __builtin_amdgcn_s_setprio(0);
    float tm = sv[0];
    #pragma unroll
    for(int r=1;r<16;++r) tm = fmaxf(tm, sv[r]);
    tm = fmaxf(tm, __shfl_xor(tm, 32));
    if(__any(tm > mrun + 8.f)){
      float mnew = fmaxf(mrun, tm);
      float alpha = __expf(mrun - mnew);
      lrun *= alpha;
      #pragma unroll
      for(int cb=0;cb<4;++cb)
        #pragma unroll
        for(int r=0;r<16;++r) acc[cb][r] *= alpha;
      mrun = mnew;
    }
    float ps = 0.f;
    #pragma unroll
    for(int r=0;r<16;++r){ float pv = __expf(sv[r] - mrun); sv[r] = pv; ps += pv; }
    ps += __shfl_xor(ps, 32);
    lrun += ps;
    u32 pk[8];
    #pragma unroll
    for(int i=0;i<8;++i){
      u32 w_;
      asm("v_cvt_pk_bf16_f32 %0, %1, %2" : "=v"(w_) : "v"(sv[2*i]), "v"(sv[2*i+1]));
      pk[i] = w_;
    }
    asm volatile("v_permlane32_swap_b32 %0, %1" : "+v"(pk[0]), "+v"(pk[2]));
    asm volatile("v_permlane32_swap_b32 %0, %1" : "+v"(pk[1]), "+v"(pk[3]));
    asm volatile("v_permlane32_swap_b32 %0, %1" : "+v"(pk[4]), "+v"(pk[6]));
    asm volatile("v_permlane32_swap_b32 %0, %1" : "+v"(pk[5]), "+v"(pk[7]));
    u32x4 w0 = {pk[0], pk[1], pk[2], pk[3]};
    u32x4 w1 = {pk[4], pk[5], pk[6], pk[7]};
    s16x8 pb0 = __builtin_bit_cast(s16x8, w0);
    s16x8 pb1 = __builtin_bit_cast(s16x8, w1);
    __builtin_amdgcn_s_setprio(1);
    #pragma unroll
    for(int cb=0;cb<4;++cb){
      s16x8 va0 = *(const s16x8*)(Vb + swz((u32)(((cb*2+0)*64+lane)<<4)));
      s16x8 va1 = *(const s16x8*)(Vb + swz((u32)(((cb*2+1)*64+lane)<<4)));
      acc[cb] = __builtin_amdgcn_mfma_f32_32x32x16_bf16(va0, pb0, acc[cb], 0, 0, 0);
      acc[cb] = __builtin_amdgcn_mfma_f32_32x32x16_bf16(va1, pb1, acc[cb], 0, 0, 0);
    }
    __builtin_amdgcn_s_setprio(0);
    // ---- write next group into buf p^1
    if(j<31){
      #pragma unroll
      for(int i=0;i<6;++i) *(s16x8*)(lds + (p^1)*49152 + sdo[i]) = stg[i];
    }
    __syncthreads();
  }

  // stats
  if(hi == 0){
    sst[wid*64 + ml*2 + 0] = mrun;
    sst[wid*64 + ml*2 + 1] = lrun;
  }
  __syncthreads();
  // per-lane merge weights for (g, ml) over splits
  float mws[4], sws[4], Mx = -3.0e38f;
  #pragma unroll
  for(int s2=0;s2<4;++s2){ mws[s2] = sst[(s2*2+g)*64 + ml*2 + 0]; Mx = fmaxf(Mx, mws[s2]); }
  float lstar = 0.f;
  #pragma unroll
  for(int s2=0;s2<4;++s2){ sws[s2] = __expf(mws[s2]-Mx); lstar += sst[(s2*2+g)*64 + ml*2 + 1]*sws[s2]; }
  float inv = 1.f/lstar;
  int m = mbase + ml;

  // 4-phase combine over cb; dump region aliases staging buffers (32KB)
  float* dump = (float*)lds;
  #pragma unroll
  for(int cb=0;cb<4;++cb){
    #pragma unroll
    for(int r=0;r<16;++r)
      dump[wid*1024 + r*64 + lane] = acc[cb][r];
    __syncthreads();
    int c0 = cb*32 + s*8 + 4*hi;
    size_t rb2 = ((size_t)((b*4 + cb)*4096) + m)*32 + s*8 + 4*hi;
    s16x4 xr = *(const s16x4*)(x2b + rb2);
    s16x4 ir = *(const s16x4*)(idbb + rb2);
    #pragma unroll
    for(int q=0;q<4;++q){
      int r = s*4 + q;
      float O = 0.f;
      #pragma unroll
      for(int s2=0;s2<4;++s2) O += sws[s2]*dump[(s2*2+g)*1024 + r*64 + lane];
      float val = O*inv + b2f(xr[q]) + b2f(ir[q]);
      out[((size_t)b*128 + c0 + q)*4096 + m] = lrelu(val);
    }
    __syncthreads();
  }
}

extern "C" void kernel_launch(void* const* d_in, const int* in_sizes, int n_in,
                              void* d_out, int out_size, void* d_ws, size_t ws_size,
                              hipStream_t stream) {
  const float* x    = (const float*)d_in[0];
  const float* W_up = (const float*)d_in[1];
  const float* b_up = (const float*)d_in[2];
  const float* g0   = (const float*)d_in[3];
  const float* be0  = (const float*)d_in[4];
  const float* m0   = (const float*)d_in[5];
  const float* v0   = (const float*)d_in[6];
  const float* W_r0 = (const float*)d_in[7];
  const float* g1   = (const float*)d_in[8];
  const float* be1  = (const float*)d_in[9];
  const float* m1   = (const float*)d_in[10];
  const float* v1   = (const float*)d_in[11];
  const float* W_r1 = (const float*)d_in[12];
  const float* g2   = (const float*)d_in[13];
  const float* be2  = (const float*)d_in[14];
  const float* m2   = (const float*)d_in[15];
  const float* v2   = (const float*)d_in[16];
  const float* Wq   = (const float*)d_in[17];
  const float* bq   = (const float*)d_in[18];
  const float* Wk   = (const float*)d_in[19];
  const float* bk   = (const float*)d_in[20];
  const float* Wv   = (const float*)d_in[21];
  const float* bv   = (const float*)d_in[22];

  float* ws = (float*)d_ws;
  u16* xh   = (u16*)(ws + 0);         // [4][8][1024][32]
  u16* ub   = (u16*)(ws + 524288);    // [4][8][4096][32]
  u16* idbb = (u16*)(ws + 2621440);   // [4][4][4096][32]
  u16* x1b  = (u16*)(ws + 3670016);   // [4][4][4096][32]
  u16* x2b  = (u16*)(ws + 4718592);   // [4][4][4096][32]
  u16* qbf  = (u16*)(ws + 5767168);   // [4,4096,64]
  u16* kbf  = (u16*)(ws + 6291456);   // [4,4096,64]
  u16* vbf  = (u16*)(ws + 6815744);   // [4,128,4096]
  u16* wtu  = (u16*)(ws + 7864320);   // [8][9][128][32]
  u16* wtr0 = (u16*)(ws + 8011776);   // [4][9][128][32]
  u16* wtr1 = (u16*)(ws + 8085504);   // [4][9][128][32]
  u16* wqk  = (u16*)(ws + 8159232);   // [4][128][32]
  u16* wvb  = (u16*)(ws + 8167424);   // [4][128][32]
  float* out = (float*)d_out;

  // weight transforms (fused)
  k_wall<<<2432, 256, 0, stream>>>(W_up, W_r0, W_r1, Wq, Wk, Wv, wtu, wtr0, wtr1, wqk, wvb);
  // input layout + upsample
  k_tr<<<1024, 256, 0, stream>>>(x, xh);
  k_up8<<<2048, 256, 0, stream>>>(xh, ub);
  // convs (MFMA implicit GEMM, blocked coalesced loads, round-10 structure)
  k_cmfma<256><<<512, 128, 0, stream>>>(ub, wtu, b_up, g0, be0, m0, v0, idbb);
  k_cmfma<128><<<512, 128, 0, stream>>>(idbb, wtr0, nullptr, g1, be1, m1, v1, x1b);
  k_cmfma<128><<<512, 128, 0, stream>>>(x1b, wtr1, nullptr, g2, be2, m2, v2, x2b);
  // projections
  k_projqk<<<512, 128, 0, stream>>>(x2b, wqk, bq, bk, qbf, kbf);
  k_projv<<<512, 128, 0, stream>>>(x2b, wvb, bv, vbf);
  // attention + residuals + lrelu (LDS-staged, swizzled)
  k_fattn4<<<256, 512, 0, stream>>>(qbf, kbf, vbf, x2b, idbb, out);
}